// Round 6
// baseline (598.249 us; speedup 1.0000x reference)
//
#include <hip/hip_runtime.h>
#include <math.h>

#define B_ 4
#define C_ 256
#define CI_ 128
#define N_ 4096
#define QT_ 64
#define KT_ 64
#define KH_ 2048
#define NITER (KH_ / KT_)     // 32
#define KSTRIDE 264   // 256 + 8 pad (verified round 3)
#define VSTRIDE 72    // 64 + 8 pad (verified round 3)
constexpr float EPS_ = 1e-5f;

typedef __attribute__((ext_vector_type(8))) short bfrag;
typedef __attribute__((ext_vector_type(4))) float f4;

__device__ __forceinline__ unsigned short bf16r(float x) {
    unsigned u = __float_as_uint(x);
    u += 0x7FFFu + ((u >> 16) & 1u);
    return (unsigned short)(u >> 16);
}
__device__ __forceinline__ unsigned pack_bf16(float a, float b) {
    unsigned ua = __float_as_uint(a); ua += 0x7FFFu + ((ua >> 16) & 1u);
    unsigned ub = __float_as_uint(b); ub += 0x7FFFu + ((ub >> 16) & 1u);
    return (ua >> 16) | (ub & 0xFFFF0000u);
}

// ---------------- K0: zero BN accumulators -------------------------------
__global__ void zero_acc(float* __restrict__ sums) {
    int t = threadIdx.x;
    sums[t] = 0.f;
    sums[t + 256] = 0.f;
}

// ---------------- K1: x[b][c][n] fp32 -> xt[b][n][c] bf16 ----------------
__global__ __launch_bounds__(256) void make_xt(const float* __restrict__ x,
                                               unsigned short* __restrict__ xt) {
    int n  = blockIdx.x * 256 + threadIdx.x;
    int c0 = blockIdx.y * 8;
    int b  = blockIdx.z;
    const float* xb = x + (size_t)b * C_ * N_;
    unsigned short buf[8];
#pragma unroll
    for (int c = 0; c < 8; c++) buf[c] = bf16r(xb[(c0 + c) * N_ + n]);   // coalesced
    uint4 v;
    v.x = buf[0] | ((unsigned)buf[1] << 16);
    v.y = buf[2] | ((unsigned)buf[3] << 16);
    v.z = buf[4] | ((unsigned)buf[5] << 16);
    v.w = buf[6] | ((unsigned)buf[7] << 16);
    *(uint4*)&xt[((size_t)b * N_ + n) * C_ + c0] = v;
}

// ---------------- K2: g conv from x (fp32) -> gx bf16 [b][o][m] ----------
__global__ __launch_bounds__(256) void gconv(const float* __restrict__ x,
                                             const float* __restrict__ gw,
                                             const float* __restrict__ gb,
                                             unsigned short* __restrict__ gx) {
    int m  = blockIdx.x * 256 + threadIdx.x;
    int o0 = blockIdx.y * 16;
    int b  = blockIdx.z;
    const float* xb = x + (size_t)b * C_ * N_;
    float acc[16];
#pragma unroll
    for (int o = 0; o < 16; o++) acc[o] = gb[o0 + o];
    for (int c = 0; c < C_; c++) {
        float xv = xb[c * N_ + m];                    // coalesced along m
#pragma unroll
        for (int o = 0; o < 16; o++) acc[o] += gw[(o0 + o) * C_ + c] * xv;  // uniform
    }
#pragma unroll
    for (int o = 0; o < 16; o++)
        gx[((size_t)b * CI_ + o0 + o) * N_ + m] = bf16r(acc[o]);            // coalesced
}

// ---------------- K3: MFMA flash attention (QT=64, 2 K-halves) -----------
// grid 512 = 64 qtiles x 4 b x 2 halves -> 2 blocks/CU. Each wave owns 16 q.
// St[m][q] = K.Q (A=Ks LDS, B=Q regs); P -> Ps[q][m] LDS; Yt[ci][q] = Vt.P.
// Round-3-verified fragment mappings with the t-dimension removed.
__global__ __launch_bounds__(256, 2) void attn(const unsigned short* __restrict__ xt,
                                               const unsigned short* __restrict__ gx,
                                               float* __restrict__ Yp,
                                               float* __restrict__ ml) {
    __shared__ __align__(16) unsigned short Ks[64 * KSTRIDE];    // 33 KB
    __shared__ __align__(16) unsigned short Vs[128 * VSTRIDE];   // 18 KB
    __shared__ __align__(16) unsigned short Ps[64 * VSTRIDE];    // 9 KB

    const int tid  = threadIdx.x;
    const int lane = tid & 63, w = tid >> 6;
    const int quad = lane >> 4, ql = lane & 15;
    const int half = blockIdx.x & 1;
    const int b    = (blockIdx.x >> 1) & 3;      // (half,b) constant per XCD residue
    const int qt   = blockIdx.x >> 3;
    const int n0   = qt * QT_;
    const int kbase = half * KH_;
    const unsigned short* xtb = xt + (size_t)b * N_ * C_;
    const unsigned short* gxb = gx + (size_t)b * CI_ * N_;

    // Q B-frags: loop-invariant (32 VGPRs); wave w owns q rows n0+16w..+16
    bfrag qb[8];
#pragma unroll
    for (int ks = 0; ks < 8; ks++)
        qb[ks] = *(const bfrag*)(xtb + (size_t)(n0 + 16 * w + ql) * C_ + 32 * ks + quad * 8);

    f4 yacc[8];
    const f4 zero4 = {0.f, 0.f, 0.f, 0.f};
#pragma unroll
    for (int i = 0; i < 8; i++) yacc[i] = zero4;
    float mrun = -INFINITY, lrun = 0.f;

    // K prologue prefetch (exact: same loads as loop-top staging)
    uint4 kreg[8];
#pragma unroll
    for (int r = 0; r < 8; r++)
        kreg[r] = *(const uint4*)(xtb + (size_t)(kbase + 8 * r + (tid >> 5)) * C_ + (tid & 31) * 8);

    for (int it = 0; it < NITER; ++it) {
        const int m0 = kbase + it * KT_;
        uint4 vreg[4];
#pragma unroll
        for (int r = 0; r < 4; r++)
            vreg[r] = *(const uint4*)(gxb + (size_t)(32 * r + (tid >> 3)) * N_ + m0 + (tid & 7) * 8);

        __syncthreads();                       // prev-iter LDS reads done
#pragma unroll
        for (int r = 0; r < 8; r++)
            *(uint4*)&Ks[(8 * r + (tid >> 5)) * KSTRIDE + (tid & 31) * 8] = kreg[r];
#pragma unroll
        for (int r = 0; r < 4; r++)
            *(uint4*)&Vs[(32 * r + (tid >> 3)) * VSTRIDE + (tid & 7) * 8] = vreg[r];
        __syncthreads();                       // tiles visible

        // prefetch next K tile (overlaps compute)
        if (it + 1 < NITER) {
#pragma unroll
            for (int r = 0; r < 8; r++)
                kreg[r] = *(const uint4*)(xtb + (size_t)(m0 + KT_ + 8 * r + (tid >> 5)) * C_ + (tid & 31) * 8);
        }

        // ---- St = K.Q : 32 mfma / wave ----
        f4 sacc[4];
#pragma unroll
        for (int i = 0; i < 4; i++) sacc[i] = zero4;
#pragma unroll
        for (int ks = 0; ks < 8; ks++) {
            bfrag ka[4];
#pragma unroll
            for (int i = 0; i < 4; i++)
                ka[i] = *(const bfrag*)&Ks[(16 * i + ql) * KSTRIDE + 32 * ks + quad * 8];
#pragma unroll
            for (int i = 0; i < 4; i++)
                sacc[i] = __builtin_amdgcn_mfma_f32_16x16x32_bf16(ka[i], qb[ks], sacc[i], 0, 0, 0);
        }

        // ---- online softmax over m (in-lane + cross-quad shuffles) ----
        float mx = -INFINITY;
#pragma unroll
        for (int i = 0; i < 4; i++)
#pragma unroll
            for (int r = 0; r < 4; r++) mx = fmaxf(mx, sacc[i][r]);
        mx = fmaxf(mx, __shfl_xor(mx, 16, 64));
        mx = fmaxf(mx, __shfl_xor(mx, 32, 64));
        float mn = fmaxf(mrun, mx);
        float alpha = __expf(mrun - mn);       // -inf -> 0 first iter
        mrun = mn;
        lrun *= alpha;
        if (__any(alpha != 1.f)) {
#pragma unroll
            for (int i = 0; i < 8; i++) {
                yacc[i][0] *= alpha; yacc[i][1] *= alpha;
                yacc[i][2] *= alpha; yacc[i][3] *= alpha;
            }
        }

        // ---- P = exp(S-m) -> Ps[q][m]; l per-lane (reduced in epilogue) ----
        {
            int q = 16 * w + ql;
            float lsum = 0.f;
#pragma unroll
            for (int i = 0; i < 4; i++) {
                float p0 = __expf(sacc[i][0] - mrun);
                float p1 = __expf(sacc[i][1] - mrun);
                float p2 = __expf(sacc[i][2] - mrun);
                float p3 = __expf(sacc[i][3] - mrun);
                lsum += (p0 + p1) + (p2 + p3);
                int idx = q * VSTRIDE + 16 * i + 4 * quad;   // m = 16i+4quad+r
                *(unsigned*)&Ps[idx]     = pack_bf16(p0, p1);
                *(unsigned*)&Ps[idx + 2] = pack_bf16(p2, p3);
            }
            lrun += lsum;
        }

        // ---- Yt += Vt.P : 16 mfma / wave ----
#pragma unroll
        for (int ks = 0; ks < 2; ks++) {
            bfrag pb, va[8];
            pb = *(const bfrag*)&Ps[(16 * w + ql) * VSTRIDE + 32 * ks + quad * 8];
#pragma unroll
            for (int i = 0; i < 8; i++)
                va[i] = *(const bfrag*)&Vs[(16 * i + ql) * VSTRIDE + 32 * ks + quad * 8];
#pragma unroll
            for (int i = 0; i < 8; i++)
                yacc[i] = __builtin_amdgcn_mfma_f32_16x16x32_bf16(va[i], pb, yacc[i], 0, 0, 0);
        }
    }

    // ---- epilogue: finish l reduction, store fp32 numerator + (m,l) ----
    lrun += __shfl_xor(lrun, 16, 64);
    lrun += __shfl_xor(lrun, 32, 64);
    {
        int n = n0 + 16 * w + ql;
#pragma unroll
        for (int i = 0; i < 8; i++)
#pragma unroll
            for (int r = 0; r < 4; r++) {
                int ci = 16 * i + quad * 4 + r;
                Yp[(((size_t)half * 4 + b) * CI_ + ci) * N_ + n] = yacc[i][r];
            }
        if (quad == 0) {
            ml[(((size_t)half * 4 + b) * N_ + n) * 2]     = mrun;
            ml[(((size_t)half * 4 + b) * N_ + n) * 2 + 1] = lrun;
        }
    }
}

// ---------------- K4: fused merge (2 halves) + W conv + BN stats ---------
// grid (N/64, B), 256 thr. Merged y lives only in LDS.
// FIX vs rounds 4/5: two co-passes per wave -> all 256 output channels.
__global__ __launch_bounds__(256) void merge_wconv(const float* __restrict__ Yp,
                                                   const float* __restrict__ ml,
                                                   const float* __restrict__ Ww,
                                                   const float* __restrict__ Wb,
                                                   float* __restrict__ wy,
                                                   float* __restrict__ sums) {
    __shared__ float Ys[64 * 132];   // [n][ci], pad 132
    __shared__ float wqs[2][64];

    const int tid = threadIdx.x;
    const int nl = tid & 63, g = tid >> 6;       // g = wave id
    const int n0 = blockIdx.x * 64, b = blockIdx.y;
    const int n = n0 + nl;

    if (tid < 64) {
        float m0 = ml[((size_t)b * N_ + n0 + tid) * 2];
        float l0 = ml[((size_t)b * N_ + n0 + tid) * 2 + 1];
        float m1 = ml[(((size_t)4 + b) * N_ + n0 + tid) * 2];
        float l1 = ml[(((size_t)4 + b) * N_ + n0 + tid) * 2 + 1];
        float mm = fmaxf(m0, m1);
        float e0 = __expf(m0 - mm), e1 = __expf(m1 - mm);
        float inv = 1.f / (e0 * l0 + e1 * l1);
        wqs[0][tid] = e0 * inv;
        wqs[1][tid] = e1 * inv;
    }
    __syncthreads();

    // merge halves into LDS y[n][ci]; wave g covers ci in [32g, 32g+32) (CI=128 ✓)
    float w0 = wqs[0][nl], w1 = wqs[1][nl];
#pragma unroll
    for (int j = 0; j < 32; j += 4) {
        float4 v;
        float* vv = (float*)&v;
#pragma unroll
        for (int k = 0; k < 4; k++) {
            int ci = g * 32 + j + k;
            size_t base = ((size_t)b * CI_ + ci) * N_ + n;
            vv[k] = w0 * Yp[base] + w1 * Yp[(size_t)4 * CI_ * N_ + base];
        }
        *(float4*)&Ys[nl * 132 + g * 32 + j] = v;
    }
    __syncthreads();

    // wconv: two passes; wave g covers co in {128*pass + 32g + j} -> 256 total
#pragma unroll
    for (int pass = 0; pass < 2; pass++) {
        const int cobase = 128 * pass + 32 * g;
        float acc[32];
#pragma unroll
        for (int j = 0; j < 32; j++) acc[j] = Wb[cobase + j];
        for (int cb = 0; cb < CI_; cb += 4) {
            float4 yv = *(const float4*)&Ys[nl * 132 + cb];
#pragma unroll
            for (int j = 0; j < 32; j++) {
                const float* wr = Ww + (size_t)(cobase + j) * CI_ + cb;   // uniform
                acc[j] += wr[0] * yv.x + wr[1] * yv.y + wr[2] * yv.z + wr[3] * yv.w;
            }
        }
#pragma unroll
        for (int j = 0; j < 32; j++)
            wy[((size_t)b * C_ + cobase + j) * N_ + n] = acc[j];          // coalesced

        // BN partial sums: shuffle-reduce over 64 n-lanes, 1 atomic per co
#pragma unroll
        for (int j = 0; j < 32; j++) {
            float s1 = acc[j], s2 = acc[j] * acc[j];
#pragma unroll
            for (int off = 32; off > 0; off >>= 1) {
                s1 += __shfl_down(s1, off, 64);
                s2 += __shfl_down(s2, off, 64);
            }
            if (nl == 0) {
                atomicAdd(&sums[cobase + j], s1);
                atomicAdd(&sums[256 + cobase + j], s2);
            }
        }
    }
}

// ---------------- K5: BN finalize + residual (float4, wy aliased to out) -
__global__ __launch_bounds__(256) void bn_finalize(float* __restrict__ wy,
                                                   const float* __restrict__ x,
                                                   const float* __restrict__ sums,
                                                   const float* __restrict__ gamma,
                                                   const float* __restrict__ beta,
                                                   float* __restrict__ out) {
    int n4 = blockIdx.x * 256 + threadIdx.x;     // float4 index, N/4 per (co,b)
    int co = blockIdx.y;
    int b  = blockIdx.z;
    float cnt  = (float)(B_ * N_);
    float mean = sums[co] / cnt;
    float var  = sums[256 + co] / cnt - mean * mean;
    float sc   = rsqrtf(var + EPS_) * gamma[co];
    float bt   = beta[co];
    size_t idx = ((size_t)b * C_ + co) * N_ + (size_t)n4 * 4;
    float4 wv = *(const float4*)&wy[idx];
    float4 xv = *(const float4*)&x[idx];
    float4 o;
    o.x = (wv.x - mean) * sc + bt + xv.x;
    o.y = (wv.y - mean) * sc + bt + xv.y;
    o.z = (wv.z - mean) * sc + bt + xv.z;
    o.w = (wv.w - mean) * sc + bt + xv.w;
    *(float4*)&out[idx] = o;
}

extern "C" void kernel_launch(void* const* d_in, const int* in_sizes, int n_in,
                              void* d_out, int out_size, void* d_ws, size_t ws_size,
                              hipStream_t stream) {
    const float* x     = (const float*)d_in[0];
    const float* gw    = (const float*)d_in[1];
    const float* gb    = (const float*)d_in[2];
    const float* Ww    = (const float*)d_in[3];
    const float* Wb    = (const float*)d_in[4];
    const float* gamma = (const float*)d_in[5];
    const float* beta  = (const float*)d_in[6];
    float* out = (float*)d_out;
    float* ws  = (float*)d_ws;

    // ws (floats): total 7,406,080 = 29.6 MB (round-3 proven footprint)
    unsigned short* xt  = (unsigned short*)ws;              // 8 MB  [0, 2,097,152)
    unsigned short* gxb = (unsigned short*)(ws + 2097152);  // 4 MB  [2,097,152, 3,145,728)
    float* Yp   = ws + 3145728;                             // 16 MB [3,145,728, 7,340,032)
    float* ml   = ws + 7340032;                             // 256 KB [7,340,032, 7,405,568)
    float* sums = ws + 7405568;                             // 2 KB
    float* wy   = out;                                      // wy aliased onto d_out

    hipLaunchKernelGGL(zero_acc, dim3(1), dim3(256), 0, stream, sums);
    hipLaunchKernelGGL(make_xt, dim3(16, 32, 4), dim3(256), 0, stream, x, xt);
    hipLaunchKernelGGL(gconv, dim3(16, 8, 4), dim3(256), 0, stream, x, gw, gb, gxb);
    hipLaunchKernelGGL(attn, dim3(512), dim3(256), 0, stream, xt, gxb, Yp, ml);
    hipLaunchKernelGGL(merge_wconv, dim3(64, 4), dim3(256), 0, stream, Yp, ml, Ww, Wb, wy, sums);
    hipLaunchKernelGGL(bn_finalize, dim3(4, 256, 4), dim3(256), 0, stream, wy, x, sums, gamma, beta, out);
}

// Round 7
// 500.357 us; speedup vs baseline: 1.1956x; 1.1956x over previous
//
#include <hip/hip_runtime.h>
#include <math.h>

#define B_ 4
#define C_ 256
#define CI_ 128
#define N_ 4096
#define QT_ 128
#define KT_ 64
#define KH_ 2048
#define NITER (KH_ / KT_)     // 32
#define KSTRIDE 264   // 256 + 8 pad (verified round 3)
#define VSTRIDE 72    // 64 + 8 pad (verified round 3)
constexpr float EPS_ = 1e-5f;

typedef __attribute__((ext_vector_type(8))) short bfrag;
typedef __attribute__((ext_vector_type(4))) float f4;

__device__ __forceinline__ unsigned short bf16r(float x) {
    unsigned u = __float_as_uint(x);
    u += 0x7FFFu + ((u >> 16) & 1u);
    return (unsigned short)(u >> 16);
}
__device__ __forceinline__ unsigned pack_bf16(float a, float b) {
    unsigned ua = __float_as_uint(a); ua += 0x7FFFu + ((ua >> 16) & 1u);
    unsigned ub = __float_as_uint(b); ub += 0x7FFFu + ((ub >> 16) & 1u);
    return (ua >> 16) | (ub & 0xFFFF0000u);
}

// ---------------- K0: zero BN accumulators -------------------------------
__global__ void zero_acc(float* __restrict__ sums) {
    int t = threadIdx.x;
    sums[t] = 0.f;
    sums[t + 256] = 0.f;
}

// ---------------- K1: x[b][c][n] fp32 -> xt[b][n][c] bf16 ----------------
__global__ __launch_bounds__(256) void make_xt(const float* __restrict__ x,
                                               unsigned short* __restrict__ xt) {
    int n  = blockIdx.x * 256 + threadIdx.x;
    int c0 = blockIdx.y * 8;
    int b  = blockIdx.z;
    const float* xb = x + (size_t)b * C_ * N_;
    unsigned short buf[8];
#pragma unroll
    for (int c = 0; c < 8; c++) buf[c] = bf16r(xb[(c0 + c) * N_ + n]);   // coalesced
    uint4 v;
    v.x = buf[0] | ((unsigned)buf[1] << 16);
    v.y = buf[2] | ((unsigned)buf[3] << 16);
    v.z = buf[4] | ((unsigned)buf[5] << 16);
    v.w = buf[6] | ((unsigned)buf[7] << 16);
    *(uint4*)&xt[((size_t)b * N_ + n) * C_ + c0] = v;
}

// ---------------- K2: g conv from x (fp32) -> gx bf16 [b][o][m] ----------
// (weights indexed by blockIdx -> provably uniform -> s_loads; verified fast)
__global__ __launch_bounds__(256) void gconv(const float* __restrict__ x,
                                             const float* __restrict__ gw,
                                             const float* __restrict__ gb,
                                             unsigned short* __restrict__ gx) {
    int m  = blockIdx.x * 256 + threadIdx.x;
    int o0 = blockIdx.y * 16;
    int b  = blockIdx.z;
    const float* xb = x + (size_t)b * C_ * N_;
    float acc[16];
#pragma unroll
    for (int o = 0; o < 16; o++) acc[o] = gb[o0 + o];
    for (int c = 0; c < C_; c++) {
        float xv = xb[c * N_ + m];                    // coalesced along m
#pragma unroll
        for (int o = 0; o < 16; o++) acc[o] += gw[(o0 + o) * C_ + c] * xv;  // s_load
    }
#pragma unroll
    for (int o = 0; o < 16; o++)
        gx[((size_t)b * CI_ + o0 + o) * N_ + m] = bf16r(acc[o]);            // coalesced
}

// ---------------- K3: MFMA flash attention (QT=128, 512 thr, prefetch) ---
// grid 256 = 32 qtiles x 4 b x 2 halves; 8 waves/block = 2 waves/SIMD.
// Wave w owns q rows n0+16w..+16 (round-6-verified band mapping).
// St[m][q] = K.Q (A=Ks LDS, B=Q regs); P -> Ps[q][m] LDS; Yt[ci][q] = Vt.P.
__global__ __launch_bounds__(512, 2) void attn(const unsigned short* __restrict__ xt,
                                               const unsigned short* __restrict__ gx,
                                               float* __restrict__ Yp,
                                               float* __restrict__ ml) {
    __shared__ __align__(16) unsigned short Ks[64 * KSTRIDE];    // 33 KB
    __shared__ __align__(16) unsigned short Vs[128 * VSTRIDE];   // 18 KB
    __shared__ __align__(16) unsigned short Ps[128 * VSTRIDE];   // 18 KB

    const int tid  = threadIdx.x;
    const int lane = tid & 63, w = tid >> 6;     // w in 0..7
    const int quad = lane >> 4, ql = lane & 15;
    const int half = blockIdx.x & 1;
    const int b    = (blockIdx.x & 7) >> 1;      // (half,b) constant per XCD residue
    const int qt   = blockIdx.x >> 3;
    const int n0   = qt * QT_;
    const int kbase = half * KH_;
    const unsigned short* xtb = xt + (size_t)b * N_ * C_;
    const unsigned short* gxb = gx + (size_t)b * CI_ * N_;

    // Q B-frags: loop-invariant (32 VGPRs); wave w owns q rows n0+16w..+16
    bfrag qb[8];
#pragma unroll
    for (int ks = 0; ks < 8; ks++)
        qb[ks] = *(const bfrag*)(xtb + (size_t)(n0 + 16 * w + ql) * C_ + 32 * ks + quad * 8);

    f4 yacc[8];
    const f4 zero4 = {0.f, 0.f, 0.f, 0.f};
#pragma unroll
    for (int i = 0; i < 8; i++) yacc[i] = zero4;
    float mrun = -INFINITY, lrun = 0.f;

    // prologue prefetch: K tile (2048 uint4 over 512 thr) + V tile (1024 uint4)
    uint4 kreg[4], vreg[2];
#pragma unroll
    for (int r = 0; r < 4; r++) {
        int idx = r * 512 + tid;                 // row = idx>>5 (0..63), blk = idx&31
        kreg[r] = *(const uint4*)(xtb + (size_t)(kbase + (idx >> 5)) * C_ + (idx & 31) * 8);
    }
#pragma unroll
    for (int r = 0; r < 2; r++) {
        int idx = r * 512 + tid;                 // row = idx>>3 (0..127), blk = idx&7
        vreg[r] = *(const uint4*)(gxb + (size_t)(idx >> 3) * N_ + kbase + (idx & 7) * 8);
    }

    for (int it = 0; it < NITER; ++it) {
        const int m0 = kbase + it * KT_;

        __syncthreads();                       // prev-iter LDS reads done
#pragma unroll
        for (int r = 0; r < 4; r++) {
            int idx = r * 512 + tid;
            *(uint4*)&Ks[(idx >> 5) * KSTRIDE + (idx & 31) * 8] = kreg[r];
        }
#pragma unroll
        for (int r = 0; r < 2; r++) {
            int idx = r * 512 + tid;
            *(uint4*)&Vs[(idx >> 3) * VSTRIDE + (idx & 7) * 8] = vreg[r];
        }
        __syncthreads();                       // tiles visible

        // prefetch next iter's K+V (overlaps entire compute phase)
        if (it + 1 < NITER) {
#pragma unroll
            for (int r = 0; r < 4; r++) {
                int idx = r * 512 + tid;
                kreg[r] = *(const uint4*)(xtb + (size_t)(m0 + KT_ + (idx >> 5)) * C_ + (idx & 31) * 8);
            }
#pragma unroll
            for (int r = 0; r < 2; r++) {
                int idx = r * 512 + tid;
                vreg[r] = *(const uint4*)(gxb + (size_t)(idx >> 3) * N_ + m0 + KT_ + (idx & 7) * 8);
            }
        }

        // ---- St = K.Q : 32 mfma / wave ----
        f4 sacc[4];
#pragma unroll
        for (int i = 0; i < 4; i++) sacc[i] = zero4;
#pragma unroll
        for (int ks = 0; ks < 8; ks++) {
            bfrag ka[4];
#pragma unroll
            for (int i = 0; i < 4; i++)
                ka[i] = *(const bfrag*)&Ks[(16 * i + ql) * KSTRIDE + 32 * ks + quad * 8];
#pragma unroll
            for (int i = 0; i < 4; i++)
                sacc[i] = __builtin_amdgcn_mfma_f32_16x16x32_bf16(ka[i], qb[ks], sacc[i], 0, 0, 0);
        }

        // ---- online softmax over m (in-lane + cross-quad shuffles) ----
        float mx = -INFINITY;
#pragma unroll
        for (int i = 0; i < 4; i++)
#pragma unroll
            for (int r = 0; r < 4; r++) mx = fmaxf(mx, sacc[i][r]);
        mx = fmaxf(mx, __shfl_xor(mx, 16, 64));
        mx = fmaxf(mx, __shfl_xor(mx, 32, 64));
        float mn = fmaxf(mrun, mx);
        float alpha = __expf(mrun - mn);       // -inf -> 0 first iter
        mrun = mn;
        lrun *= alpha;
        if (__any(alpha != 1.f)) {
#pragma unroll
            for (int i = 0; i < 8; i++) {
                yacc[i][0] *= alpha; yacc[i][1] *= alpha;
                yacc[i][2] *= alpha; yacc[i][3] *= alpha;
            }
        }

        // ---- P = exp(S-m) -> Ps[q][m]; l per-lane (reduced in epilogue) ----
        {
            int q = 16 * w + ql;
            float lsum = 0.f;
#pragma unroll
            for (int i = 0; i < 4; i++) {
                float p0 = __expf(sacc[i][0] - mrun);
                float p1 = __expf(sacc[i][1] - mrun);
                float p2 = __expf(sacc[i][2] - mrun);
                float p3 = __expf(sacc[i][3] - mrun);
                lsum += (p0 + p1) + (p2 + p3);
                int idx = q * VSTRIDE + 16 * i + 4 * quad;   // m = 16i+4quad+r
                *(unsigned*)&Ps[idx]     = pack_bf16(p0, p1);
                *(unsigned*)&Ps[idx + 2] = pack_bf16(p2, p3);
            }
            lrun += lsum;
        }

        // ---- Yt += Vt.P : 16 mfma / wave ----
#pragma unroll
        for (int ks = 0; ks < 2; ks++) {
            bfrag pb, va[8];
            pb = *(const bfrag*)&Ps[(16 * w + ql) * VSTRIDE + 32 * ks + quad * 8];
#pragma unroll
            for (int i = 0; i < 8; i++)
                va[i] = *(const bfrag*)&Vs[(16 * i + ql) * VSTRIDE + 32 * ks + quad * 8];
#pragma unroll
            for (int i = 0; i < 8; i++)
                yacc[i] = __builtin_amdgcn_mfma_f32_16x16x32_bf16(va[i], pb, yacc[i], 0, 0, 0);
        }
    }

    // ---- epilogue: finish l reduction, store fp32 numerator + (m,l) ----
    lrun += __shfl_xor(lrun, 16, 64);
    lrun += __shfl_xor(lrun, 32, 64);
    {
        int n = n0 + 16 * w + ql;
#pragma unroll
        for (int i = 0; i < 8; i++)
#pragma unroll
            for (int r = 0; r < 4; r++) {
                int ci = 16 * i + quad * 4 + r;
                Yp[(((size_t)half * 4 + b) * CI_ + ci) * N_ + n] = yacc[i][r];
            }
        if (quad == 0) {
            ml[(((size_t)half * 4 + b) * N_ + n) * 2]     = mrun;
            ml[(((size_t)half * 4 + b) * N_ + n) * 2 + 1] = lrun;
        }
    }
}

// ---------------- K4: fused merge (2 halves) + W conv + BN stats ---------
// grid (N/64, B, 2): blockIdx.z = co-half. Merged y lives only in LDS.
// Weight addresses forced wave-uniform via readfirstlane -> s_load_dwordx4.
__global__ __launch_bounds__(256) void merge_wconv(const float* __restrict__ Yp,
                                                   const float* __restrict__ ml,
                                                   const float* __restrict__ Ww,
                                                   const float* __restrict__ Wb,
                                                   float* __restrict__ wy,
                                                   float* __restrict__ sums) {
    __shared__ float Ys[64 * 132];   // [n][ci], pad 132
    __shared__ float wqs[2][64];

    const int tid = threadIdx.x;
    const int nl = tid & 63, g = tid >> 6;       // g = wave id
    const int n0 = blockIdx.x * 64, b = blockIdx.y, z = blockIdx.z;
    const int n = n0 + nl;

    if (tid < 64) {
        float m0 = ml[((size_t)b * N_ + n0 + tid) * 2];
        float l0 = ml[((size_t)b * N_ + n0 + tid) * 2 + 1];
        float m1 = ml[(((size_t)4 + b) * N_ + n0 + tid) * 2];
        float l1 = ml[(((size_t)4 + b) * N_ + n0 + tid) * 2 + 1];
        float mm = fmaxf(m0, m1);
        float e0 = __expf(m0 - mm), e1 = __expf(m1 - mm);
        float inv = 1.f / (e0 * l0 + e1 * l1);
        wqs[0][tid] = e0 * inv;
        wqs[1][tid] = e1 * inv;
    }
    __syncthreads();

    // merge halves into LDS y[n][ci]; wave g covers ci in [32g, 32g+32)
    // (duplicated across the 2 z-blocks — cheap, keeps them independent)
    float w0 = wqs[0][nl], w1 = wqs[1][nl];
#pragma unroll
    for (int j = 0; j < 32; j += 4) {
        float4 v;
        float* vv = (float*)&v;
#pragma unroll
        for (int k = 0; k < 4; k++) {
            int ci = g * 32 + j + k;
            size_t base = ((size_t)b * CI_ + ci) * N_ + n;
            vv[k] = w0 * Yp[base] + w1 * Yp[(size_t)4 * CI_ * N_ + base];
        }
        *(float4*)&Ys[nl * 132 + g * 32 + j] = v;
    }
    __syncthreads();

    // wconv: this block covers co in [128z, 128z+128); wave g -> 32 co.
    const int cobase = 128 * z + 32 * g;
    float acc[32];
#pragma unroll
    for (int j = 0; j < 32; j++) acc[j] = Wb[cobase + j];
    for (int cb = 0; cb < CI_; cb += 4) {
        float4 yv = *(const float4*)&Ys[nl * 132 + cb];
#pragma unroll
        for (int j = 0; j < 32; j++) {
            // readfirstlane -> provably uniform address -> s_load_dwordx4
            int co_u = __builtin_amdgcn_readfirstlane(cobase + j);
            const float* wr = Ww + (size_t)co_u * CI_ + cb;
            acc[j] += wr[0] * yv.x + wr[1] * yv.y + wr[2] * yv.z + wr[3] * yv.w;
        }
    }
#pragma unroll
    for (int j = 0; j < 32; j++)
        wy[((size_t)b * C_ + cobase + j) * N_ + n] = acc[j];          // coalesced

    // BN partial sums: shuffle-reduce over 64 n-lanes, 1 atomic per co
#pragma unroll
    for (int j = 0; j < 32; j++) {
        float s1 = acc[j], s2 = acc[j] * acc[j];
#pragma unroll
        for (int off = 32; off > 0; off >>= 1) {
            s1 += __shfl_down(s1, off, 64);
            s2 += __shfl_down(s2, off, 64);
        }
        if (nl == 0) {
            atomicAdd(&sums[cobase + j], s1);
            atomicAdd(&sums[256 + cobase + j], s2);
        }
    }
}

// ---------------- K5: BN finalize + residual (float4, wy aliased to out) -
__global__ __launch_bounds__(256) void bn_finalize(float* __restrict__ wy,
                                                   const float* __restrict__ x,
                                                   const float* __restrict__ sums,
                                                   const float* __restrict__ gamma,
                                                   const float* __restrict__ beta,
                                                   float* __restrict__ out) {
    int n4 = blockIdx.x * 256 + threadIdx.x;     // float4 index, N/4 per (co,b)
    int co = blockIdx.y;
    int b  = blockIdx.z;
    float cnt  = (float)(B_ * N_);
    float mean = sums[co] / cnt;
    float var  = sums[256 + co] / cnt - mean * mean;
    float sc   = rsqrtf(var + EPS_) * gamma[co];
    float bt   = beta[co];
    size_t idx = ((size_t)b * C_ + co) * N_ + (size_t)n4 * 4;
    float4 wv = *(const float4*)&wy[idx];
    float4 xv = *(const float4*)&x[idx];
    float4 o;
    o.x = (wv.x - mean) * sc + bt + xv.x;
    o.y = (wv.y - mean) * sc + bt + xv.y;
    o.z = (wv.z - mean) * sc + bt + xv.z;
    o.w = (wv.w - mean) * sc + bt + xv.w;
    *(float4*)&out[idx] = o;
}

extern "C" void kernel_launch(void* const* d_in, const int* in_sizes, int n_in,
                              void* d_out, int out_size, void* d_ws, size_t ws_size,
                              hipStream_t stream) {
    const float* x     = (const float*)d_in[0];
    const float* gw    = (const float*)d_in[1];
    const float* gb    = (const float*)d_in[2];
    const float* Ww    = (const float*)d_in[3];
    const float* Wb    = (const float*)d_in[4];
    const float* gamma = (const float*)d_in[5];
    const float* beta  = (const float*)d_in[6];
    float* out = (float*)d_out;
    float* ws  = (float*)d_ws;

    // ws (floats): total 7,406,080 = 29.6 MB (round-3 proven footprint)
    unsigned short* xt  = (unsigned short*)ws;              // 8 MB  [0, 2,097,152)
    unsigned short* gxb = (unsigned short*)(ws + 2097152);  // 4 MB  [2,097,152, 3,145,728)
    float* Yp   = ws + 3145728;                             // 16 MB [3,145,728, 7,340,032)
    float* ml   = ws + 7340032;                             // 256 KB [7,340,032, 7,405,568)
    float* sums = ws + 7405568;                             // 2 KB
    float* wy   = out;                                      // wy aliased onto d_out

    hipLaunchKernelGGL(zero_acc, dim3(1), dim3(256), 0, stream, sums);
    hipLaunchKernelGGL(make_xt, dim3(16, 32, 4), dim3(256), 0, stream, x, xt);
    hipLaunchKernelGGL(gconv, dim3(16, 8, 4), dim3(256), 0, stream, x, gw, gb, gxb);
    hipLaunchKernelGGL(attn, dim3(256), dim3(512), 0, stream, xt, gxb, Yp, ml);
    hipLaunchKernelGGL(merge_wconv, dim3(64, 4, 2), dim3(256), 0, stream, Yp, ml, Ww, Wb, wy, sums);
    hipLaunchKernelGGL(bn_finalize, dim3(4, 256, 4), dim3(256), 0, stream, wy, x, sums, gamma, beta, out);
}

// Round 8
// 299.405 us; speedup vs baseline: 1.9981x; 1.6712x over previous
//
#include <hip/hip_runtime.h>
#include <math.h>

#define B_ 4
#define C_ 256
#define CI_ 128
#define N_ 4096
#define QT_ 128
#define KT_ 64
#define KH_ 2048
#define NITER (KH_ / KT_)     // 32
#define KSTRIDE 264   // 256 + 8 pad (verified round 3)
#define VSTRIDE 72    // 64 + 8 pad (verified round 3)
#define WSTR 66       // Ws [k][co'] pad: 64+2
#define YSTR 68       // Ys [ci][n] pad: 64+4 (b128-aligned, 2-way max)
constexpr float EPS_ = 1e-5f;

typedef __attribute__((ext_vector_type(8))) short bfrag;
typedef __attribute__((ext_vector_type(4))) float f4;

__device__ __forceinline__ unsigned short bf16r(float x) {
    unsigned u = __float_as_uint(x);
    u += 0x7FFFu + ((u >> 16) & 1u);
    return (unsigned short)(u >> 16);
}
__device__ __forceinline__ unsigned pack_bf16(float a, float b) {
    unsigned ua = __float_as_uint(a); ua += 0x7FFFu + ((ua >> 16) & 1u);
    unsigned ub = __float_as_uint(b); ub += 0x7FFFu + ((ub >> 16) & 1u);
    return (ua >> 16) | (ub & 0xFFFF0000u);
}

// ---------------- K0: zero BN accumulators -------------------------------
__global__ void zero_acc(float* __restrict__ sums) {
    int t = threadIdx.x;
    sums[t] = 0.f;
    sums[t + 256] = 0.f;
}

// ---------------- K1: x[b][c][n] fp32 -> xt[b][n][c] bf16 ----------------
__global__ __launch_bounds__(256) void make_xt(const float* __restrict__ x,
                                               unsigned short* __restrict__ xt) {
    int n  = blockIdx.x * 256 + threadIdx.x;
    int c0 = blockIdx.y * 8;
    int b  = blockIdx.z;
    const float* xb = x + (size_t)b * C_ * N_;
    unsigned short buf[8];
#pragma unroll
    for (int c = 0; c < 8; c++) buf[c] = bf16r(xb[(c0 + c) * N_ + n]);   // coalesced
    uint4 v;
    v.x = buf[0] | ((unsigned)buf[1] << 16);
    v.y = buf[2] | ((unsigned)buf[3] << 16);
    v.z = buf[4] | ((unsigned)buf[5] << 16);
    v.w = buf[6] | ((unsigned)buf[7] << 16);
    *(uint4*)&xt[((size_t)b * N_ + n) * C_ + c0] = v;
}

// ---------------- K2: g conv from x (fp32) -> gx bf16 [b][o][m] ----------
__global__ __launch_bounds__(256) void gconv(const float* __restrict__ x,
                                             const float* __restrict__ gw,
                                             const float* __restrict__ gb,
                                             unsigned short* __restrict__ gx) {
    int m  = blockIdx.x * 256 + threadIdx.x;
    int o0 = blockIdx.y * 16;
    int b  = blockIdx.z;
    const float* xb = x + (size_t)b * C_ * N_;
    float acc[16];
#pragma unroll
    for (int o = 0; o < 16; o++) acc[o] = gb[o0 + o];
    for (int c = 0; c < C_; c++) {
        float xv = xb[c * N_ + m];                    // coalesced along m
#pragma unroll
        for (int o = 0; o < 16; o++) acc[o] += gw[(o0 + o) * C_ + c] * xv;  // s_load
    }
#pragma unroll
    for (int o = 0; o < 16; o++)
        gx[((size_t)b * CI_ + o0 + o) * N_ + m] = bf16r(acc[o]);            // coalesced
}

// ---------------- K3: MFMA flash attention (double-buffered LDS) ---------
// grid 256 = 32 qtiles x 4 b x 2 halves; 512 thr = 8 waves; 1 block/CU.
// ONE barrier per K-iter: write buf[nxt] overlaps compute on buf[cur].
// Fragment mappings byte-identical to round-3/7 verified forms.
__global__ __launch_bounds__(512, 1) void attn(const unsigned short* __restrict__ xt,
                                               const unsigned short* __restrict__ gx,
                                               float* __restrict__ Yp,
                                               float* __restrict__ ml) {
    __shared__ __align__(16) unsigned short Ks[2][64 * KSTRIDE];    // 2 x 33 KB
    __shared__ __align__(16) unsigned short Vs[2][128 * VSTRIDE];   // 2 x 18 KB
    __shared__ __align__(16) unsigned short Ps[128 * VSTRIDE];      // 18 KB

    const int tid  = threadIdx.x;
    const int lane = tid & 63, w = tid >> 6;     // w in 0..7
    const int quad = lane >> 4, ql = lane & 15;
    const int half = blockIdx.x & 1;
    const int b    = (blockIdx.x & 7) >> 1;      // (half,b) constant per XCD residue
    const int qt   = blockIdx.x >> 3;
    const int n0   = qt * QT_;
    const int kbase = half * KH_;
    const unsigned short* xtb = xt + (size_t)b * N_ * C_;
    const unsigned short* gxb = gx + (size_t)b * CI_ * N_;

    // Q B-frags: loop-invariant (32 VGPRs); wave w owns q rows n0+16w..+16
    bfrag qb[8];
#pragma unroll
    for (int ks = 0; ks < 8; ks++)
        qb[ks] = *(const bfrag*)(xtb + (size_t)(n0 + 16 * w + ql) * C_ + 32 * ks + quad * 8);

    f4 yacc[8];
    const f4 zero4 = {0.f, 0.f, 0.f, 0.f};
#pragma unroll
    for (int i = 0; i < 8; i++) yacc[i] = zero4;
    float mrun = -INFINITY, lrun = 0.f;

    // prologue: load tile0 -> regs -> buf0; load tile1 -> regs
    uint4 kreg[4], vreg[2];
#pragma unroll
    for (int r = 0; r < 4; r++) {
        int idx = r * 512 + tid;
        kreg[r] = *(const uint4*)(xtb + (size_t)(kbase + (idx >> 5)) * C_ + (idx & 31) * 8);
    }
#pragma unroll
    for (int r = 0; r < 2; r++) {
        int idx = r * 512 + tid;
        vreg[r] = *(const uint4*)(gxb + (size_t)(idx >> 3) * N_ + kbase + (idx & 7) * 8);
    }
#pragma unroll
    for (int r = 0; r < 4; r++) {
        int idx = r * 512 + tid;
        *(uint4*)&Ks[0][(idx >> 5) * KSTRIDE + (idx & 31) * 8] = kreg[r];
    }
#pragma unroll
    for (int r = 0; r < 2; r++) {
        int idx = r * 512 + tid;
        *(uint4*)&Vs[0][(idx >> 3) * VSTRIDE + (idx & 7) * 8] = vreg[r];
    }
#pragma unroll
    for (int r = 0; r < 4; r++) {
        int idx = r * 512 + tid;
        kreg[r] = *(const uint4*)(xtb + (size_t)(kbase + KT_ + (idx >> 5)) * C_ + (idx & 31) * 8);
    }
#pragma unroll
    for (int r = 0; r < 2; r++) {
        int idx = r * 512 + tid;
        vreg[r] = *(const uint4*)(gxb + (size_t)(idx >> 3) * N_ + kbase + KT_ + (idx & 7) * 8);
    }
    __syncthreads();                             // buf0 ready

    for (int it = 0; it < NITER; ++it) {
        const int cur = it & 1, nxt = cur ^ 1;

        // write tile it+1 (in regs) into buf[nxt]; overlaps compute on buf[cur]
        if (it + 1 < NITER) {
#pragma unroll
            for (int r = 0; r < 4; r++) {
                int idx = r * 512 + tid;
                *(uint4*)&Ks[nxt][(idx >> 5) * KSTRIDE + (idx & 31) * 8] = kreg[r];
            }
#pragma unroll
            for (int r = 0; r < 2; r++) {
                int idx = r * 512 + tid;
                *(uint4*)&Vs[nxt][(idx >> 3) * VSTRIDE + (idx & 7) * 8] = vreg[r];
            }
        }
        // prefetch tile it+2 -> regs (overlaps compute)
        if (it + 2 < NITER) {
            const int t0 = kbase + (it + 2) * KT_;
#pragma unroll
            for (int r = 0; r < 4; r++) {
                int idx = r * 512 + tid;
                kreg[r] = *(const uint4*)(xtb + (size_t)(t0 + (idx >> 5)) * C_ + (idx & 31) * 8);
            }
#pragma unroll
            for (int r = 0; r < 2; r++) {
                int idx = r * 512 + tid;
                vreg[r] = *(const uint4*)(gxb + (size_t)(idx >> 3) * N_ + t0 + (idx & 7) * 8);
            }
        }

        // ---- St = K.Q : 32 mfma / wave ----
        f4 sacc[4];
#pragma unroll
        for (int i = 0; i < 4; i++) sacc[i] = zero4;
#pragma unroll
        for (int ks = 0; ks < 8; ks++) {
            bfrag ka[4];
#pragma unroll
            for (int i = 0; i < 4; i++)
                ka[i] = *(const bfrag*)&Ks[cur][(16 * i + ql) * KSTRIDE + 32 * ks + quad * 8];
#pragma unroll
            for (int i = 0; i < 4; i++)
                sacc[i] = __builtin_amdgcn_mfma_f32_16x16x32_bf16(ka[i], qb[ks], sacc[i], 0, 0, 0);
        }

        // ---- online softmax over m (in-lane + cross-quad shuffles) ----
        float mx = -INFINITY;
#pragma unroll
        for (int i = 0; i < 4; i++)
#pragma unroll
            for (int r = 0; r < 4; r++) mx = fmaxf(mx, sacc[i][r]);
        mx = fmaxf(mx, __shfl_xor(mx, 16, 64));
        mx = fmaxf(mx, __shfl_xor(mx, 32, 64));
        float mn = fmaxf(mrun, mx);
        float alpha = __expf(mrun - mn);       // -inf -> 0 first iter
        mrun = mn;
        lrun *= alpha;
        if (__any(alpha != 1.f)) {
#pragma unroll
            for (int i = 0; i < 8; i++) {
                yacc[i][0] *= alpha; yacc[i][1] *= alpha;
                yacc[i][2] *= alpha; yacc[i][3] *= alpha;
            }
        }

        // ---- P = exp(S-m) -> Ps[q][m] (wave-private rows, no barrier) ----
        {
            int q = 16 * w + ql;
            float lsum = 0.f;
#pragma unroll
            for (int i = 0; i < 4; i++) {
                float p0 = __expf(sacc[i][0] - mrun);
                float p1 = __expf(sacc[i][1] - mrun);
                float p2 = __expf(sacc[i][2] - mrun);
                float p3 = __expf(sacc[i][3] - mrun);
                lsum += (p0 + p1) + (p2 + p3);
                int idx = q * VSTRIDE + 16 * i + 4 * quad;   // m = 16i+4quad+r
                *(unsigned*)&Ps[idx]     = pack_bf16(p0, p1);
                *(unsigned*)&Ps[idx + 2] = pack_bf16(p2, p3);
            }
            lrun += lsum;
        }

        // ---- Yt += Vt.P : 16 mfma / wave ----
#pragma unroll
        for (int ks = 0; ks < 2; ks++) {
            bfrag pb, va[8];
            pb = *(const bfrag*)&Ps[(16 * w + ql) * VSTRIDE + 32 * ks + quad * 8];
#pragma unroll
            for (int i = 0; i < 8; i++)
                va[i] = *(const bfrag*)&Vs[cur][(16 * i + ql) * VSTRIDE + 32 * ks + quad * 8];
#pragma unroll
            for (int i = 0; i < 8; i++)
                yacc[i] = __builtin_amdgcn_mfma_f32_16x16x32_bf16(va[i], pb, yacc[i], 0, 0, 0);
        }

        __syncthreads();   // buf[nxt] writes done; buf[cur] reads done
    }

    // ---- epilogue: finish l reduction, store fp32 numerator + (m,l) ----
    lrun += __shfl_xor(lrun, 16, 64);
    lrun += __shfl_xor(lrun, 32, 64);
    {
        int n = n0 + 16 * w + ql;
#pragma unroll
        for (int i = 0; i < 8; i++)
#pragma unroll
            for (int r = 0; r < 4; r++) {
                int ci = 16 * i + quad * 4 + r;
                Yp[(((size_t)half * 4 + b) * CI_ + ci) * N_ + n] = yacc[i][r];
            }
        if (quad == 0) {
            ml[(((size_t)half * 4 + b) * N_ + n) * 2]     = mrun;
            ml[(((size_t)half * 4 + b) * N_ + n) * 2 + 1] = lrun;
        }
    }
}

// ---------------- K4: fused merge + W conv + BN stats (LDS GEMM) ---------
// grid (N/64, B, 4z): block covers 64 n x 64 co (co' = co - 64z).
// Weights AND merged y staged in LDS once; thread tile 4co x 4n, fp32.
__global__ __launch_bounds__(256, 2) void merge_wconv(const float* __restrict__ Yp,
                                                      const float* __restrict__ ml,
                                                      const float* __restrict__ Ww,
                                                      const float* __restrict__ Wb,
                                                      float* __restrict__ wy,
                                                      float* __restrict__ sums) {
    __shared__ float Ws[128 * WSTR];   // [k][co'] 33 KB
    __shared__ float Ys[128 * YSTR];   // [ci][n]  34 KB
    __shared__ float wqs[2][64];

    const int tid = threadIdx.x;
    const int nl = tid & 63, cig = tid >> 6;     // merge-phase roles
    const int lane = tid & 63, w = tid >> 6;
    const int ng = lane & 15, cg = lane >> 4;    // compute-phase roles
    const int n0 = blockIdx.x * 64, b = blockIdx.y, z = blockIdx.z;

    // ---- stage Ws transposed: Ws[k][co'], co' in [0,64) ----
#pragma unroll
    for (int r = 0; r < 8; r++) {
        int idx = r * 256 + tid;
        int cop = idx >> 5;            // 0..63
        int k4  = idx & 31;            // 0..31
        float4 f = *(const float4*)&Ww[(size_t)(64 * z + cop) * CI_ + 4 * k4];  // coalesced
        Ws[(4 * k4 + 0) * WSTR + cop] = f.x;
        Ws[(4 * k4 + 1) * WSTR + cop] = f.y;
        Ws[(4 * k4 + 2) * WSTR + cop] = f.z;
        Ws[(4 * k4 + 3) * WSTR + cop] = f.w;
    }

    // ---- merge weights per n ----
    if (tid < 64) {
        float m0 = ml[((size_t)b * N_ + n0 + tid) * 2];
        float l0 = ml[((size_t)b * N_ + n0 + tid) * 2 + 1];
        float m1 = ml[(((size_t)4 + b) * N_ + n0 + tid) * 2];
        float l1 = ml[(((size_t)4 + b) * N_ + n0 + tid) * 2 + 1];
        float mm = fmaxf(m0, m1);
        float e0 = __expf(m0 - mm), e1 = __expf(m1 - mm);
        float inv = 1.f / (e0 * l0 + e1 * l1);
        wqs[0][tid] = e0 * inv;
        wqs[1][tid] = e1 * inv;
    }
    __syncthreads();

    // ---- merge halves into Ys[ci][n]; wave cig covers ci [32cig,32cig+32) ----
    float w0 = wqs[0][nl], w1 = wqs[1][nl];
#pragma unroll
    for (int j = 0; j < 32; j++) {
        int ci = cig * 32 + j;
        size_t base = ((size_t)b * CI_ + ci) * N_ + n0 + nl;   // coalesced over nl
        Ys[ci * YSTR + nl] = w0 * Yp[base] + w1 * Yp[(size_t)4 * CI_ * N_ + base];
    }
    __syncthreads();

    // ---- GEMM: acc[4co][4n]; co' = 16w + 4cg + j, n = n0 + 4ng + d ----
    const int cop0 = 16 * w + 4 * cg;
    float acc[4][4];
#pragma unroll
    for (int j = 0; j < 4; j++) {
        float bias = Wb[64 * z + cop0 + j];
#pragma unroll
        for (int d = 0; d < 4; d++) acc[j][d] = bias;
    }
#pragma unroll 4
    for (int k = 0; k < CI_; k++) {
        float4 yv = *(const float4*)&Ys[k * YSTR + 4 * ng];     // 2-way max
        float4 wv = *(const float4*)&Ws[k * WSTR + cop0];       // broadcast
        acc[0][0] += wv.x * yv.x; acc[0][1] += wv.x * yv.y;
        acc[0][2] += wv.x * yv.z; acc[0][3] += wv.x * yv.w;
        acc[1][0] += wv.y * yv.x; acc[1][1] += wv.y * yv.y;
        acc[1][2] += wv.y * yv.z; acc[1][3] += wv.y * yv.w;
        acc[2][0] += wv.z * yv.x; acc[2][1] += wv.z * yv.y;
        acc[2][2] += wv.z * yv.z; acc[2][3] += wv.z * yv.w;
        acc[3][0] += wv.w * yv.x; acc[3][1] += wv.w * yv.y;
        acc[3][2] += wv.w * yv.z; acc[3][3] += wv.w * yv.w;
    }

    // ---- store wy + BN partial sums ----
#pragma unroll
    for (int j = 0; j < 4; j++) {
        int co = 64 * z + cop0 + j;
        float4 st;
        st.x = acc[j][0]; st.y = acc[j][1]; st.z = acc[j][2]; st.w = acc[j][3];
        *(float4*)&wy[((size_t)b * C_ + co) * N_ + n0 + 4 * ng] = st;   // coalesced

        float s1 = acc[j][0] + acc[j][1] + acc[j][2] + acc[j][3];
        float s2 = acc[j][0] * acc[j][0] + acc[j][1] * acc[j][1]
                 + acc[j][2] * acc[j][2] + acc[j][3] * acc[j][3];
#pragma unroll
        for (int off = 1; off < 16; off <<= 1) {        // reduce over ng (16 lanes)
            s1 += __shfl_xor(s1, off, 64);
            s2 += __shfl_xor(s2, off, 64);
        }
        if (ng == 0) {
            atomicAdd(&sums[co], s1);
            atomicAdd(&sums[256 + co], s2);
        }
    }
}

// ---------------- K5: BN finalize + residual (float4, wy aliased to out) -
__global__ __launch_bounds__(256) void bn_finalize(float* __restrict__ wy,
                                                   const float* __restrict__ x,
                                                   const float* __restrict__ sums,
                                                   const float* __restrict__ gamma,
                                                   const float* __restrict__ beta,
                                                   float* __restrict__ out) {
    int n4 = blockIdx.x * 256 + threadIdx.x;     // float4 index, N/4 per (co,b)
    int co = blockIdx.y;
    int b  = blockIdx.z;
    float cnt  = (float)(B_ * N_);
    float mean = sums[co] / cnt;
    float var  = sums[256 + co] / cnt - mean * mean;
    float sc   = rsqrtf(var + EPS_) * gamma[co];
    float bt   = beta[co];
    size_t idx = ((size_t)b * C_ + co) * N_ + (size_t)n4 * 4;
    float4 wv = *(const float4*)&wy[idx];
    float4 xv = *(const float4*)&x[idx];
    float4 o;
    o.x = (wv.x - mean) * sc + bt + xv.x;
    o.y = (wv.y - mean) * sc + bt + xv.y;
    o.z = (wv.z - mean) * sc + bt + xv.z;
    o.w = (wv.w - mean) * sc + bt + xv.w;
    *(float4*)&out[idx] = o;
}

extern "C" void kernel_launch(void* const* d_in, const int* in_sizes, int n_in,
                              void* d_out, int out_size, void* d_ws, size_t ws_size,
                              hipStream_t stream) {
    const float* x     = (const float*)d_in[0];
    const float* gw    = (const float*)d_in[1];
    const float* gb    = (const float*)d_in[2];
    const float* Ww    = (const float*)d_in[3];
    const float* Wb    = (const float*)d_in[4];
    const float* gamma = (const float*)d_in[5];
    const float* beta  = (const float*)d_in[6];
    float* out = (float*)d_out;
    float* ws  = (float*)d_ws;

    // ws (floats): total 7,406,080 = 29.6 MB (round-3 proven footprint)
    unsigned short* xt  = (unsigned short*)ws;              // 8 MB  [0, 2,097,152)
    unsigned short* gxb = (unsigned short*)(ws + 2097152);  // 4 MB  [2,097,152, 3,145,728)
    float* Yp   = ws + 3145728;                             // 16 MB [3,145,728, 7,340,032)
    float* ml   = ws + 7340032;                             // 256 KB [7,340,032, 7,405,568)
    float* sums = ws + 7405568;                             // 2 KB
    float* wy   = out;                                      // wy aliased onto d_out

    hipLaunchKernelGGL(zero_acc, dim3(1), dim3(256), 0, stream, sums);
    hipLaunchKernelGGL(make_xt, dim3(16, 32, 4), dim3(256), 0, stream, x, xt);
    hipLaunchKernelGGL(gconv, dim3(16, 8, 4), dim3(256), 0, stream, x, gw, gb, gxb);
    hipLaunchKernelGGL(attn, dim3(256), dim3(512), 0, stream, xt, gxb, Yp, ml);
    hipLaunchKernelGGL(merge_wconv, dim3(64, 4, 4), dim3(256), 0, stream, Yp, ml, Ww, Wb, wy, sums);
    hipLaunchKernelGGL(bn_finalize, dim3(4, 256, 4), dim3(256), 0, stream, wy, x, sums, gamma, beta, out);
}